// Round 16
// baseline (410.718 us; speedup 1.0000x reference)
//
#include <hip/hip_runtime.h>
#include <cstdint>
#include <cmath>

// Problem: z[32768,512] f32, emb[4096,512] f32
#define N_ROWS 32768
#define DIM    512
#define KCODES 4096
#define SPLITS 4
#define CPS    (KCODES / SPLITS)   // 1024 codes per split
#define KCL    (CPS / 64)          // 16 code-chunks per split
#define BM     128                 // rows per block = 4 waves x 32
#define TAU    2e-3f               // gate threshold on exact noisy scores (proven r5/r8)
#define CAP    1024                // max refined rows (expect ~466; wide headroom)
#define RQ     8                   // rescan rows per thread (ILP + e-reuse)

typedef _Float16 f16x8 __attribute__((ext_vector_type(8)));
typedef float    f32x4 __attribute__((ext_vector_type(4)));

// ---- ws layout (float units) ----
// [0, 1048576): f16 codebook image, 256 tiles x 16KB (4 MB)
#define OFF_NH  1048576                        // negHalf[4096] = -0.5||e||^2
#define OFF_EN  (OFF_NH + KCODES)              // Enp[4096] (np-exact ||e||^2)
#define OFF_R1  (OFF_EN + KCODES)              // R1 [SPLITS][N_ROWS] f32
#define OFF_R2  (OFF_R1 + SPLITS * N_ROWS)     // R2 [SPLITS][N_ROWS] f32
#define OFF_I1  (OFF_R2 + SPLITS * N_ROWS)     // I1 [SPLITS][N_ROWS] i32
#define OFF_FI  (OFF_I1 + SPLITS * N_ROWS)     // flagidx[N_ROWS] i32 (0 or pos+1)
#define OFF_BI  (OFF_FI + N_ROWS)              // best idx[N_ROWS] i32
#define OFF_BS  (OFF_BI + N_ROWS)              // blockSums[2048]
#define OFF_CT  (OFF_BS + 2048)                // counter[4] i32
#define OFF_LR  (OFF_CT + 4)                   // listRow[CAP] i32
#define OFF_LS  (OFF_LR + CAP)                 // listS[CAP] f32
#define OFF_SL  (OFF_LS + CAP)                 // slots[CAP] u64 (even offset -> 8B aligned)

__device__ __forceinline__ bool lexGT(float v1, int i1, float v2, int i2) {
  return (v1 > v2) || (v1 == v2 && i1 < i2);
}

__device__ __forceinline__ void gload16(const void* g, void* l) {
  __builtin_amdgcn_global_load_lds(
      (const __attribute__((address_space(1))) unsigned int*)g,
      (__attribute__((address_space(3))) unsigned int*)l, 16, 0, 0);
}

// ---- numpy fp32 bit-exact helpers (verified rounds 2-5, 8-15) ----
__device__ float np_sumsq_512(const float* __restrict__ a) {
#pragma clang fp contract(off)
  float B[4];
#pragma unroll
  for (int t = 0; t < 4; ++t) {
    const float* p = a + t * 128;
    float r[8];
    {
      float4 x0 = *(const float4*)p;
      float4 x1 = *(const float4*)(p + 4);
      r[0] = x0.x * x0.x; r[1] = x0.y * x0.y; r[2] = x0.z * x0.z; r[3] = x0.w * x0.w;
      r[4] = x1.x * x1.x; r[5] = x1.y * x1.y; r[6] = x1.z * x1.z; r[7] = x1.w * x1.w;
    }
    for (int i = 8; i < 128; i += 8) {
      float4 x0 = *(const float4*)(p + i);
      float4 x1 = *(const float4*)(p + i + 4);
      float f[8] = {x0.x, x0.y, x0.z, x0.w, x1.x, x1.y, x1.z, x1.w};
#pragma unroll
      for (int j = 0; j < 8; ++j) {
        float sq = f[j] * f[j];
        r[j] = r[j] + sq;
      }
    }
    B[t] = ((r[0] + r[1]) + (r[2] + r[3])) + ((r[4] + r[5]) + (r[6] + r[7]));
  }
  return (B[0] + B[1]) + (B[2] + B[3]);
}

// ---- prep (fused): f16 codebook image (inverse mapping -> coalesced img
// writes) + np-exact ||e||^2 + counter zero ----
__global__ __launch_bounds__(256) void vq_prep(const float* __restrict__ emb,
                                               f16x8* __restrict__ img,
                                               float* __restrict__ Enp,
                                               float* __restrict__ negHalf,
                                               int* __restrict__ counter) {
  int gid = blockIdx.x * 256 + threadIdx.x;   // linear img f16x8 slot
  if (gid == 0) counter[0] = 0;
  if (gid < KCODES) {
    float E = np_sumsq_512(emb + (size_t)gid * DIM);
    Enp[gid] = E;
    negHalf[gid] = -0.5f * E;
  }
  // img[gid] <- (code k, d-range) per the fragment-block layout:
  // gid = T*1024 + fb*64 + lane; T=(kcg,dci), fb=(ks,ct), lane=(gh,tl)
  int T = gid >> 10, rem = gid & 1023;
  int fb = rem >> 6, lane = rem & 63;
  int kcg = T >> 2, dci = T & 3;
  int ks = fb >> 2, ct = fb & 3;
  int gh = lane >> 4, tl = lane & 15;
  int k = kcg * 64 + ct * 16 + tl;
  int d = dci * 128 + (ks * 4 + gh) * 8;
  const float* ep = emb + (size_t)k * DIM + d;
  float4 a = *(const float4*)ep;
  float4 b = *(const float4*)(ep + 4);
  float f[8] = {a.x, a.y, a.z, a.w, b.x, b.y, b.z, b.w};
  f16x8 h;
#pragma unroll
  for (int j = 0; j < 8; ++j) h[j] = (_Float16)f[j];
  img[gid] = h;
}

// ---- main: 128 rows x 1024 codes; exact top-1(+index) and top-2(score).
// r16: launch_bounds(256,4) — r15 measured 124 VGPR, which FITS the
// 128-VGPR occupancy tier (m69: steps at 64/128/256); LDS 4x32KB=128KB
// <= 160KB. 4 blocks/CU = 4 waves/SIMD doubles the independent barrier
// streams -> stall overlap (kernel is 4x off its 41us LDS-pipe wall,
// pure stall-dominated at 2 waves/SIMD). Desync rotation removed
// (r11: neutral within noise; frees a few VGPRs under the tighter cap).
__global__ __launch_bounds__(256, 4) void vq_main(const float* __restrict__ z,
                                                  const f16x8* __restrict__ img,
                                                  const float* __restrict__ negHalf,
                                                  float* __restrict__ R1s,
                                                  float* __restrict__ R2s,
                                                  int* __restrict__ I1s) {
  __shared__ f16x8 EHs[2048];   // 2 x 16KB double buffer

  const int tid  = threadIdx.x;
  const int w    = tid >> 6;
  const int lane = tid & 63;
  const int tl   = lane & 15;
  const int gh   = lane >> 4;
  const int bid  = blockIdx.x;
  const int rb   = bid >> 2;       // row-block 0..255
  const int sp   = bid & 3;        // code split 0..3
  const int m0   = rb * BM;

  // resident A: 2 row-tiles x 16 K-chunks of f16x8
  f16x8 zh[2][16];
#pragma unroll
  for (int rt = 0; rt < 2; ++rt) {
    const float* zp = z + (size_t)(m0 + w * 32 + rt * 16 + tl) * DIM + gh * 8;
#pragma unroll
    for (int c = 0; c < 16; ++c) {
      float4 a = *(const float4*)(zp + c * 32);
      float4 b = *(const float4*)(zp + c * 32 + 4);
      float f[8] = {a.x, a.y, a.z, a.w, b.x, b.y, b.z, b.w};
      f16x8 h;
#pragma unroll
      for (int j = 0; j < 8; ++j) h[j] = (_Float16)f[j];
      zh[rt][c] = h;
    }
  }

  // exact running top-1 (score+uniform code base) and top-2 score per row
  float R1[8], R2[8];
  int   I1u[8];
#pragma unroll
  for (int i = 0; i < 8; ++i) { R1[i] = -INFINITY; R2[i] = -INFINITY; I1u[i] = 0x7fffffff; }

  const f16x8* tbase = img + (size_t)sp * 64 * 1024;  // this split's 64 tiles

  // prologue: stage tile 0 into buf 0 (each wave its 4KB quarter)
  {
    const char* g = (const char*)tbase + w * 4096 + lane * 16;
    char* l = (char*)EHs + w * 4096;
#pragma unroll
    for (int i = 0; i < 4; ++i) gload16(g + i * 1024, l + i * 1024);
  }
  __syncthreads();

  for (int kcl = 0; kcl < KCL; ++kcl) {
    f32x4 acc[2][4];
#pragma unroll
    for (int ct = 0; ct < 4; ++ct) {
      float nh = negHalf[sp * CPS + kcl * 64 + ct * 16 + tl];
      acc[0][ct] = (f32x4){nh, nh, nh, nh};
      acc[1][ct] = (f32x4){nh, nh, nh, nh};
    }

#pragma unroll
    for (int dci = 0; dci < 4; ++dci) {
      const int t = kcl * 4 + dci;
      const int cur = t & 1;
      if (t + 1 < 64) {  // stage next tile into the other buffer
        const char* g = (const char*)(tbase + (size_t)(t + 1) * 1024) + w * 4096 + lane * 16;
        char* l = (char*)EHs + (cur ^ 1) * 16384 + w * 4096;
#pragma unroll
        for (int i = 0; i < 4; ++i) gload16(g + i * 1024, l + i * 1024);
      }
      const f16x8* B = EHs + cur * 1024;
#pragma unroll
      for (int ks = 0; ks < 4; ++ks) {
        {
          f16x8 bf0 = B[(ks * 4 + 0) * 64 + lane];
          f16x8 bf1 = B[(ks * 4 + 1) * 64 + lane];
          acc[0][0] = __builtin_amdgcn_mfma_f32_16x16x32_f16(zh[0][dci * 4 + ks], bf0, acc[0][0], 0, 0, 0);
          acc[1][0] = __builtin_amdgcn_mfma_f32_16x16x32_f16(zh[1][dci * 4 + ks], bf0, acc[1][0], 0, 0, 0);
          acc[0][1] = __builtin_amdgcn_mfma_f32_16x16x32_f16(zh[0][dci * 4 + ks], bf1, acc[0][1], 0, 0, 0);
          acc[1][1] = __builtin_amdgcn_mfma_f32_16x16x32_f16(zh[1][dci * 4 + ks], bf1, acc[1][1], 0, 0, 0);
        }
        {
          f16x8 bf2 = B[(ks * 4 + 2) * 64 + lane];
          f16x8 bf3 = B[(ks * 4 + 3) * 64 + lane];
          acc[0][2] = __builtin_amdgcn_mfma_f32_16x16x32_f16(zh[0][dci * 4 + ks], bf2, acc[0][2], 0, 0, 0);
          acc[1][2] = __builtin_amdgcn_mfma_f32_16x16x32_f16(zh[1][dci * 4 + ks], bf2, acc[1][2], 0, 0, 0);
          acc[0][3] = __builtin_amdgcn_mfma_f32_16x16x32_f16(zh[0][dci * 4 + ks], bf3, acc[0][3], 0, 0, 0);
          acc[1][3] = __builtin_amdgcn_mfma_f32_16x16x32_f16(zh[1][dci * 4 + ks], bf3, acc[1][3], 0, 0, 0);
        }
      }
      __syncthreads();
    }

    // exact top-1/top-2 insert: 5 VALU per candidate, branchless.
    // Candidates ascend in code order -> strict '>' keeps lowest code on ties.
#pragma unroll
    for (int ct = 0; ct < 4; ++ct) {
      const int cu = sp * CPS + kcl * 64 + ct * 16;   // uniform -> SGPR operand
#pragma unroll
      for (int rt = 0; rt < 2; ++rt)
#pragma unroll
        for (int i = 0; i < 4; ++i) {
          int r8 = rt * 4 + i;
          float v = acc[rt][ct][i];
          float u = fminf(v, R1[r8]);
          R2[r8] = fmaxf(u, R2[r8]);
          bool gt = v > R1[r8];
          R1[r8] = fmaxf(v, R1[r8]);
          I1u[r8] = gt ? cu : I1u[r8];
        }
    }
  }

  // full per-thread code, then butterfly merge across the 16 tl-lanes
  float R1f[8], R2f[8];
  int   I1f[8];
#pragma unroll
  for (int i = 0; i < 8; ++i) { R1f[i] = R1[i]; R2f[i] = R2[i]; I1f[i] = I1u[i] + tl; }

#pragma unroll
  for (int m = 1; m < 16; m <<= 1) {
#pragma unroll
    for (int i = 0; i < 8; ++i) {
      float o1 = __shfl_xor(R1f[i], m, 16);
      int   p1 = __shfl_xor(I1f[i], m, 16);
      float o2 = __shfl_xor(R2f[i], m, 16);
      R2f[i] = fmaxf(fmaxf(R2f[i], o2), fminf(R1f[i], o1));
      if (lexGT(o1, p1, R1f[i], I1f[i])) { R1f[i] = o1; I1f[i] = p1; }
    }
  }

  if (tl == 0) {
#pragma unroll
    for (int i = 0; i < 8; ++i) {
      int row = m0 + w * 32 + (i >> 2) * 16 + gh * 4 + (i & 3);
      R1s[(size_t)sp * N_ROWS + row] = R1f[i];
      R2s[(size_t)sp * N_ROWS + row] = R2f[i];
      I1s[(size_t)sp * N_ROWS + row] = I1f[i];
    }
  }
}

// ---- merge 4 splits per row; compact near-tie rows into a work list ----
__global__ __launch_bounds__(256) void vq_merge(const float* __restrict__ z,
                                                const float* __restrict__ R1s,
                                                const float* __restrict__ R2s,
                                                const int* __restrict__ I1s,
                                                int* __restrict__ flagidx,
                                                int* __restrict__ bi,
                                                float* __restrict__ outIdx,
                                                int* __restrict__ counter,
                                                int* __restrict__ listRow,
                                                float* __restrict__ listS,
                                                unsigned long long* __restrict__ slots) {
  int row = blockIdx.x * 256 + threadIdx.x;
  float bR = -INFINITY, sec = -INFINITY;
  int bI = 0x7fffffff;
#pragma unroll
  for (int s = 0; s < 4; ++s) {
    float r1 = R1s[(size_t)s * N_ROWS + row];
    float r2 = R2s[(size_t)s * N_ROWS + row];
    int   i1 = I1s[(size_t)s * N_ROWS + row];
    sec = fmaxf(fmaxf(sec, r2), fminf(bR, r1));
    if (lexGT(r1, i1, bR, bI)) { bR = r1; bI = i1; }
  }
  bi[row] = bI;
  outIdx[row] = (float)bI;
  int fi = 0;
  if (bR - sec < TAU) {
#pragma clang fp contract(off)
    int pos = atomicAdd(counter, 1);
    if (pos < CAP) {
      listRow[pos] = row;
      listS[pos]   = np_sumsq_512(z + (size_t)row * DIM);
      slots[pos]   = ~0ull;
      fi = pos + 1;
    }
  }
  flagidx[row] = fi;
}

// ---- rescan: full np-exact argmin over all 4096 codes for listed rows.
// Grid = 16 code-chunks x 128 row-groups (2048 blocks); RQ=8 rows/thread,
// single pass for n <= 1024. 8 independent fma chains hide load latency.
__global__ __launch_bounds__(256) void vq_rescan(const float* __restrict__ z,
                                                 const float* __restrict__ emb,
                                                 const float* __restrict__ Enp,
                                                 const int* __restrict__ counter,
                                                 const int* __restrict__ listRow,
                                                 const float* __restrict__ listS,
                                                 unsigned long long* __restrict__ slots) {
  __shared__ unsigned long long sred[4][RQ];
  const int tid = threadIdx.x;
  const int ci  = blockIdx.x & 15;     // code chunk (e-rows fixed per thread)
  const int gi  = blockIdx.x >> 4;     // row group 0..127
  const int c   = ci * 256 + tid;
  const float* er = emb + (size_t)c * DIM;
  const float En = Enp[c];
  int n = counter[0];
  if (n > CAP) n = CAP;
  for (int qt = gi * RQ; qt < n; qt += 128 * RQ) {
#pragma clang fp contract(off)
    int q[RQ];
    const float* zr[RQ];
#pragma unroll
    for (int j = 0; j < RQ; ++j) {
      int qq = qt + j;
      q[j] = qq < n ? qq : n - 1;       // clamp; duplicates idempotent
      zr[j] = z + (size_t)listRow[q[j]] * DIM;
    }
    float a[RQ];
#pragma unroll
    for (int j = 0; j < RQ; ++j) a[j] = 0.f;
#pragma unroll 2
    for (int d0 = 0; d0 < DIM; d0 += 4) {
      float4 e = *(const float4*)(er + d0);
#pragma unroll
      for (int j = 0; j < RQ; ++j) {
        float4 x = *(const float4*)(zr[j] + d0);
        a[j] = fmaf(x.x, e.x, a[j]);
        a[j] = fmaf(x.y, e.y, a[j]);
        a[j] = fmaf(x.z, e.z, a[j]);
        a[j] = fmaf(x.w, e.w, a[j]);
      }
    }
#pragma unroll
    for (int j = 0; j < RQ; ++j) {
      float t = listS[q[j]] + En;
      float d = t - 2.0f * a[j];
      unsigned long long p =
          ((unsigned long long)__builtin_bit_cast(unsigned int, d) << 32) | (unsigned int)c;
#pragma unroll
      for (int m = 1; m < 64; m <<= 1) {
        unsigned long long o = __shfl_xor(p, m, 64);
        p = o < p ? o : p;
      }
      if ((tid & 63) == 0) sred[tid >> 6][j] = p;
    }
    __syncthreads();
    if (tid < RQ) {
      int j = tid;
      unsigned long long b = sred[0][j];
#pragma unroll
      for (int w2 = 1; w2 < 4; ++w2) b = sred[w2][j] < b ? sred[w2][j] : b;
      atomicMin(&slots[q[j]], b);
    }
    __syncthreads();
  }
}

// ---- epilogue: resolve refined codes, gather e[best], write quantized, loss ----
__global__ __launch_bounds__(256) void vq_epi(const float* __restrict__ z,
                                              const float* __restrict__ emb,
                                              const int* __restrict__ bi,
                                              const int* __restrict__ flagidx,
                                              const unsigned long long* __restrict__ slots,
                                              float* __restrict__ out,
                                              float* __restrict__ outIdx,
                                              float* __restrict__ blockSums) {
  __shared__ float wred[4];
  int tid = threadIdx.x;
  int g = tid >> 4, tl = tid & 15;
  int row = blockIdx.x * 16 + g;
  int fi = flagidx[row];
  int code = bi[row];
  if (fi) {
    code = (int)(unsigned int)slots[fi - 1];
    if (tl == 0) outIdx[row] = (float)code;
  }
  const float* zr = z + (size_t)row * DIM;
  const float* er = emb + (size_t)code * DIM;
  float* oq = out + 1 + (size_t)row * DIM;
  float ls = 0.f;
#pragma unroll
  for (int j = 0; j < 8; ++j) {
    int d0 = (j * 16 + tl) * 4;
    float4 e = *(const float4*)(er + d0);
    float4 zz = *(const float4*)(zr + d0);
    float dx = e.x - zz.x, dy = e.y - zz.y, dz = e.z - zz.z, dw = e.w - zz.w;
    ls = fmaf(dx, dx, ls); ls = fmaf(dy, dy, ls);
    ls = fmaf(dz, dz, ls); ls = fmaf(dw, dw, ls);
    oq[d0 + 0] = e.x; oq[d0 + 1] = e.y; oq[d0 + 2] = e.z; oq[d0 + 3] = e.w;
  }
#pragma unroll
  for (int m = 1; m < 64; m <<= 1) ls += __shfl_xor(ls, m, 64);
  if ((tid & 63) == 0) wred[tid >> 6] = ls;
  __syncthreads();
  if (tid == 0) blockSums[blockIdx.x] = wred[0] + wred[1] + wred[2] + wred[3];
}

// loss = 1.25 * mean((q-z)^2); KL factor 0. 2048 partials.
__global__ __launch_bounds__(256) void vq_final(const float* __restrict__ blockSums,
                                                float* __restrict__ out) {
  __shared__ float red[256];
  int t = threadIdx.x;
  float s = 0.f;
#pragma unroll
  for (int i = 0; i < 8; ++i) s += blockSums[t + i * 256];
  red[t] = s;
  __syncthreads();
  for (int k = 128; k > 0; k >>= 1) {
    if (t < k) red[t] += red[t + k];
    __syncthreads();
  }
  if (t == 0) out[0] = red[0] * (1.25f / 16777216.0f);
}

extern "C" void kernel_launch(void* const* d_in, const int* in_sizes, int n_in,
                              void* d_out, int out_size, void* d_ws, size_t ws_size,
                              hipStream_t stream) {
  const float* z   = (const float*)d_in[0];
  const float* emb = (const float*)d_in[1];
  float* out  = (float*)d_out;
  float* wsf  = (float*)d_ws;
  f16x8* img      = (f16x8*)d_ws;
  float* negHalf  = wsf + OFF_NH;
  float* Enp      = wsf + OFF_EN;
  float* R1s      = wsf + OFF_R1;
  float* R2s      = wsf + OFF_R2;
  int*   I1s      = (int*)(wsf + OFF_I1);
  int*   flagidx  = (int*)(wsf + OFF_FI);
  int*   bi       = (int*)(wsf + OFF_BI);
  float* bsums    = wsf + OFF_BS;
  int*   counter  = (int*)(wsf + OFF_CT);
  int*   listRow  = (int*)(wsf + OFF_LR);
  float* listS    = wsf + OFF_LS;
  unsigned long long* slots = (unsigned long long*)(wsf + OFF_SL);
  float* outIdx   = out + 1 + (size_t)N_ROWS * DIM;
  (void)in_sizes; (void)n_in; (void)out_size; (void)ws_size;

  vq_prep    <<<1024, 256, 0, stream>>>(emb, img, Enp, negHalf, counter);
  vq_main    <<<1024, 256, 0, stream>>>(z, img, negHalf, R1s, R2s, I1s);
  vq_merge   <<<N_ROWS / 256, 256, 0, stream>>>(z, R1s, R2s, I1s, flagidx, bi, outIdx,
                                                counter, listRow, listS, slots);
  vq_rescan  <<<2048, 256, 0, stream>>>(z, emb, Enp, counter, listRow, listS, slots);
  vq_epi     <<<N_ROWS / 16, 256, 0, stream>>>(z, emb, bi, flagidx, slots, out, outIdx, bsums);
  vq_final   <<<1, 256, 0, stream>>>(bsums, out);
}

// Round 17
// 353.990 us; speedup vs baseline: 1.1603x; 1.1603x over previous
//
#include <hip/hip_runtime.h>
#include <cstdint>
#include <cmath>

// Problem: z[32768,512] f32, emb[4096,512] f32
#define N_ROWS 32768
#define DIM    512
#define KCODES 4096
#define SPLITS 4
#define CPS    (KCODES / SPLITS)   // 1024 codes per split
#define KCL    (CPS / 64)          // 16 code-chunks per split
#define BM     128                 // rows per block = 4 waves x 32
#define TAU    2e-3f               // gate threshold on exact noisy scores (proven r5/r8)
#define CAP    1024                // max refined rows (expect ~466; wide headroom)
#define RQ     8                   // rescan rows per thread (ILP + e-reuse)

typedef _Float16 f16x8 __attribute__((ext_vector_type(8)));
typedef float    f32x4 __attribute__((ext_vector_type(4)));

// ---- ws layout (float units) ----
// [0, 1048576): f16 codebook image, 256 tiles x 16KB (4 MB)
#define OFF_NH  1048576                        // negHalf[4096] = -0.5||e||^2
#define OFF_EN  (OFF_NH + KCODES)              // Enp[4096] (np-exact ||e||^2)
#define OFF_R1  (OFF_EN + KCODES)              // R1 [SPLITS][N_ROWS] f32
#define OFF_R2  (OFF_R1 + SPLITS * N_ROWS)     // R2 [SPLITS][N_ROWS] f32
#define OFF_I1  (OFF_R2 + SPLITS * N_ROWS)     // I1 [SPLITS][N_ROWS] i32
#define OFF_FI  (OFF_I1 + SPLITS * N_ROWS)     // flagidx[N_ROWS] i32 (0 or pos+1)
#define OFF_BI  (OFF_FI + N_ROWS)              // best idx[N_ROWS] i32
#define OFF_BS  (OFF_BI + N_ROWS)              // blockSums[2048]
#define OFF_CT  (OFF_BS + 2048)                // counter[4] i32
#define OFF_LR  (OFF_CT + 4)                   // listRow[CAP] i32
#define OFF_LS  (OFF_LR + CAP)                 // listS[CAP] f32
#define OFF_SL  (OFF_LS + CAP)                 // slots[CAP] u64 (even offset -> 8B aligned)

__device__ __forceinline__ bool lexGT(float v1, int i1, float v2, int i2) {
  return (v1 > v2) || (v1 == v2 && i1 < i2);
}

__device__ __forceinline__ void gload16(const void* g, void* l) {
  __builtin_amdgcn_global_load_lds(
      (const __attribute__((address_space(1))) unsigned int*)g,
      (__attribute__((address_space(3))) unsigned int*)l, 16, 0, 0);
}

// ---- numpy fp32 bit-exact helpers (verified rounds 2-5, 8-16) ----
__device__ float np_sumsq_512(const float* __restrict__ a) {
#pragma clang fp contract(off)
  float B[4];
#pragma unroll
  for (int t = 0; t < 4; ++t) {
    const float* p = a + t * 128;
    float r[8];
    {
      float4 x0 = *(const float4*)p;
      float4 x1 = *(const float4*)(p + 4);
      r[0] = x0.x * x0.x; r[1] = x0.y * x0.y; r[2] = x0.z * x0.z; r[3] = x0.w * x0.w;
      r[4] = x1.x * x1.x; r[5] = x1.y * x1.y; r[6] = x1.z * x1.z; r[7] = x1.w * x1.w;
    }
    for (int i = 8; i < 128; i += 8) {
      float4 x0 = *(const float4*)(p + i);
      float4 x1 = *(const float4*)(p + i + 4);
      float f[8] = {x0.x, x0.y, x0.z, x0.w, x1.x, x1.y, x1.z, x1.w};
#pragma unroll
      for (int j = 0; j < 8; ++j) {
        float sq = f[j] * f[j];
        r[j] = r[j] + sq;
      }
    }
    B[t] = ((r[0] + r[1]) + (r[2] + r[3])) + ((r[4] + r[5]) + (r[6] + r[7]));
  }
  return (B[0] + B[1]) + (B[2] + B[3]);
}

// ---- prep (fused): f16 codebook image (inverse mapping -> coalesced img
// writes) + np-exact ||e||^2 + counter zero ----
__global__ __launch_bounds__(256) void vq_prep(const float* __restrict__ emb,
                                               f16x8* __restrict__ img,
                                               float* __restrict__ Enp,
                                               float* __restrict__ negHalf,
                                               int* __restrict__ counter) {
  int gid = blockIdx.x * 256 + threadIdx.x;   // linear img f16x8 slot
  if (gid == 0) counter[0] = 0;
  if (gid < KCODES) {
    float E = np_sumsq_512(emb + (size_t)gid * DIM);
    Enp[gid] = E;
    negHalf[gid] = -0.5f * E;
  }
  // img[gid] <- (code k, d-range) per the fragment-block layout:
  // gid = T*1024 + fb*64 + lane; T=(kcg,dci), fb=(ks,ct), lane=(gh,tl)
  int T = gid >> 10, rem = gid & 1023;
  int fb = rem >> 6, lane = rem & 63;
  int kcg = T >> 2, dci = T & 3;
  int ks = fb >> 2, ct = fb & 3;
  int gh = lane >> 4, tl = lane & 15;
  int k = kcg * 64 + ct * 16 + tl;
  int d = dci * 128 + (ks * 4 + gh) * 8;
  const float* ep = emb + (size_t)k * DIM + d;
  float4 a = *(const float4*)ep;
  float4 b = *(const float4*)(ep + 4);
  float f[8] = {a.x, a.y, a.z, a.w, b.x, b.y, b.z, b.w};
  f16x8 h;
#pragma unroll
  for (int j = 0; j < 8; ++j) h[j] = (_Float16)f[j];
  img[gid] = h;
}

// ---- main: 128 rows x 1024 codes; exact top-1(+index) and top-2(score).
// r15 structure (proven 164us, MfmaUtil 38). r17 probe: launch_bounds(256,3)
// — cap = floor(512/3) = 170 regs >= the ~156 total (124 VGPR + 32 AGPR)
// this kernel needs, so NO spill is possible (r16's (256,4) cap of 128 <
// 156 forced 64-VGPR spill hell: 850MB FETCH/dispatch, 300us). If the HW
// register quantum permits 156-reg waves at 3/SIMD we get 1.5x barrier
// streams; if quanta are pow2 tiers this is a no-op and we stay at 164us.
__global__ __launch_bounds__(256, 3) void vq_main(const float* __restrict__ z,
                                                  const f16x8* __restrict__ img,
                                                  const float* __restrict__ negHalf,
                                                  float* __restrict__ R1s,
                                                  float* __restrict__ R2s,
                                                  int* __restrict__ I1s) {
  __shared__ f16x8 EHs[2048];   // 2 x 16KB double buffer

  const int tid  = threadIdx.x;
  const int w    = tid >> 6;
  const int lane = tid & 63;
  const int tl   = lane & 15;
  const int gh   = lane >> 4;
  const int bid  = blockIdx.x;
  const int rb   = bid >> 2;       // row-block 0..255
  const int sp   = bid & 3;        // code split 0..3
  const int m0   = rb * BM;

  // resident A: 2 row-tiles x 16 K-chunks of f16x8
  f16x8 zh[2][16];
#pragma unroll
  for (int rt = 0; rt < 2; ++rt) {
    const float* zp = z + (size_t)(m0 + w * 32 + rt * 16 + tl) * DIM + gh * 8;
#pragma unroll
    for (int c = 0; c < 16; ++c) {
      float4 a = *(const float4*)(zp + c * 32);
      float4 b = *(const float4*)(zp + c * 32 + 4);
      float f[8] = {a.x, a.y, a.z, a.w, b.x, b.y, b.z, b.w};
      f16x8 h;
#pragma unroll
      for (int j = 0; j < 8; ++j) h[j] = (_Float16)f[j];
      zh[rt][c] = h;
    }
  }

  // exact running top-1 (score+uniform code base) and top-2 score per row
  float R1[8], R2[8];
  int   I1u[8];
#pragma unroll
  for (int i = 0; i < 8; ++i) { R1[i] = -INFINITY; R2[i] = -INFINITY; I1u[i] = 0x7fffffff; }

  const f16x8* tbase = img + (size_t)sp * 64 * 1024;  // this split's 64 tiles

  // prologue: stage tile 0 into buf 0 (each wave its 4KB quarter)
  {
    const char* g = (const char*)tbase + w * 4096 + lane * 16;
    char* l = (char*)EHs + w * 4096;
#pragma unroll
    for (int i = 0; i < 4; ++i) gload16(g + i * 1024, l + i * 1024);
  }
  __syncthreads();

  for (int kcl = 0; kcl < KCL; ++kcl) {
    f32x4 acc[2][4];
#pragma unroll
    for (int ct = 0; ct < 4; ++ct) {
      float nh = negHalf[sp * CPS + kcl * 64 + ct * 16 + tl];
      acc[0][ct] = (f32x4){nh, nh, nh, nh};
      acc[1][ct] = (f32x4){nh, nh, nh, nh};
    }

#pragma unroll
    for (int dci = 0; dci < 4; ++dci) {
      const int t = kcl * 4 + dci;
      const int cur = t & 1;
      if (t + 1 < 64) {  // stage next tile into the other buffer
        const char* g = (const char*)(tbase + (size_t)(t + 1) * 1024) + w * 4096 + lane * 16;
        char* l = (char*)EHs + (cur ^ 1) * 16384 + w * 4096;
#pragma unroll
        for (int i = 0; i < 4; ++i) gload16(g + i * 1024, l + i * 1024);
      }
      const f16x8* B = EHs + cur * 1024;
#pragma unroll
      for (int ks = 0; ks < 4; ++ks) {
        {
          f16x8 bf0 = B[(ks * 4 + 0) * 64 + lane];
          f16x8 bf1 = B[(ks * 4 + 1) * 64 + lane];
          acc[0][0] = __builtin_amdgcn_mfma_f32_16x16x32_f16(zh[0][dci * 4 + ks], bf0, acc[0][0], 0, 0, 0);
          acc[1][0] = __builtin_amdgcn_mfma_f32_16x16x32_f16(zh[1][dci * 4 + ks], bf0, acc[1][0], 0, 0, 0);
          acc[0][1] = __builtin_amdgcn_mfma_f32_16x16x32_f16(zh[0][dci * 4 + ks], bf1, acc[0][1], 0, 0, 0);
          acc[1][1] = __builtin_amdgcn_mfma_f32_16x16x32_f16(zh[1][dci * 4 + ks], bf1, acc[1][1], 0, 0, 0);
        }
        {
          f16x8 bf2 = B[(ks * 4 + 2) * 64 + lane];
          f16x8 bf3 = B[(ks * 4 + 3) * 64 + lane];
          acc[0][2] = __builtin_amdgcn_mfma_f32_16x16x32_f16(zh[0][dci * 4 + ks], bf2, acc[0][2], 0, 0, 0);
          acc[1][2] = __builtin_amdgcn_mfma_f32_16x16x32_f16(zh[1][dci * 4 + ks], bf2, acc[1][2], 0, 0, 0);
          acc[0][3] = __builtin_amdgcn_mfma_f32_16x16x32_f16(zh[0][dci * 4 + ks], bf3, acc[0][3], 0, 0, 0);
          acc[1][3] = __builtin_amdgcn_mfma_f32_16x16x32_f16(zh[1][dci * 4 + ks], bf3, acc[1][3], 0, 0, 0);
        }
      }
      __syncthreads();
    }

    // exact top-1/top-2 insert: 5 VALU per candidate, branchless.
    // Candidates ascend in code order -> strict '>' keeps lowest code on ties.
#pragma unroll
    for (int ct = 0; ct < 4; ++ct) {
      const int cu = sp * CPS + kcl * 64 + ct * 16;   // uniform -> SGPR operand
#pragma unroll
      for (int rt = 0; rt < 2; ++rt)
#pragma unroll
        for (int i = 0; i < 4; ++i) {
          int r8 = rt * 4 + i;
          float v = acc[rt][ct][i];
          float u = fminf(v, R1[r8]);
          R2[r8] = fmaxf(u, R2[r8]);
          bool gt = v > R1[r8];
          R1[r8] = fmaxf(v, R1[r8]);
          I1u[r8] = gt ? cu : I1u[r8];
        }
    }
  }

  // full per-thread code, then butterfly merge across the 16 tl-lanes
  float R1f[8], R2f[8];
  int   I1f[8];
#pragma unroll
  for (int i = 0; i < 8; ++i) { R1f[i] = R1[i]; R2f[i] = R2[i]; I1f[i] = I1u[i] + tl; }

#pragma unroll
  for (int m = 1; m < 16; m <<= 1) {
#pragma unroll
    for (int i = 0; i < 8; ++i) {
      float o1 = __shfl_xor(R1f[i], m, 16);
      int   p1 = __shfl_xor(I1f[i], m, 16);
      float o2 = __shfl_xor(R2f[i], m, 16);
      R2f[i] = fmaxf(fmaxf(R2f[i], o2), fminf(R1f[i], o1));
      if (lexGT(o1, p1, R1f[i], I1f[i])) { R1f[i] = o1; I1f[i] = p1; }
    }
  }

  if (tl == 0) {
#pragma unroll
    for (int i = 0; i < 8; ++i) {
      int row = m0 + w * 32 + (i >> 2) * 16 + gh * 4 + (i & 3);
      R1s[(size_t)sp * N_ROWS + row] = R1f[i];
      R2s[(size_t)sp * N_ROWS + row] = R2f[i];
      I1s[(size_t)sp * N_ROWS + row] = I1f[i];
    }
  }
}

// ---- merge 4 splits per row; compact near-tie rows into a work list ----
__global__ __launch_bounds__(256) void vq_merge(const float* __restrict__ z,
                                                const float* __restrict__ R1s,
                                                const float* __restrict__ R2s,
                                                const int* __restrict__ I1s,
                                                int* __restrict__ flagidx,
                                                int* __restrict__ bi,
                                                float* __restrict__ outIdx,
                                                int* __restrict__ counter,
                                                int* __restrict__ listRow,
                                                float* __restrict__ listS,
                                                unsigned long long* __restrict__ slots) {
  int row = blockIdx.x * 256 + threadIdx.x;
  float bR = -INFINITY, sec = -INFINITY;
  int bI = 0x7fffffff;
#pragma unroll
  for (int s = 0; s < 4; ++s) {
    float r1 = R1s[(size_t)s * N_ROWS + row];
    float r2 = R2s[(size_t)s * N_ROWS + row];
    int   i1 = I1s[(size_t)s * N_ROWS + row];
    sec = fmaxf(fmaxf(sec, r2), fminf(bR, r1));
    if (lexGT(r1, i1, bR, bI)) { bR = r1; bI = i1; }
  }
  bi[row] = bI;
  outIdx[row] = (float)bI;
  int fi = 0;
  if (bR - sec < TAU) {
#pragma clang fp contract(off)
    int pos = atomicAdd(counter, 1);
    if (pos < CAP) {
      listRow[pos] = row;
      listS[pos]   = np_sumsq_512(z + (size_t)row * DIM);
      slots[pos]   = ~0ull;
      fi = pos + 1;
    }
  }
  flagidx[row] = fi;
}

// ---- rescan: full np-exact argmin over all 4096 codes for listed rows.
// Grid = 16 code-chunks x 128 row-groups (2048 blocks); RQ=8 rows/thread,
// single pass for n <= 1024. 8 independent fma chains hide load latency.
__global__ __launch_bounds__(256) void vq_rescan(const float* __restrict__ z,
                                                 const float* __restrict__ emb,
                                                 const float* __restrict__ Enp,
                                                 const int* __restrict__ counter,
                                                 const int* __restrict__ listRow,
                                                 const float* __restrict__ listS,
                                                 unsigned long long* __restrict__ slots) {
  __shared__ unsigned long long sred[4][RQ];
  const int tid = threadIdx.x;
  const int ci  = blockIdx.x & 15;     // code chunk (e-rows fixed per thread)
  const int gi  = blockIdx.x >> 4;     // row group 0..127
  const int c   = ci * 256 + tid;
  const float* er = emb + (size_t)c * DIM;
  const float En = Enp[c];
  int n = counter[0];
  if (n > CAP) n = CAP;
  for (int qt = gi * RQ; qt < n; qt += 128 * RQ) {
#pragma clang fp contract(off)
    int q[RQ];
    const float* zr[RQ];
#pragma unroll
    for (int j = 0; j < RQ; ++j) {
      int qq = qt + j;
      q[j] = qq < n ? qq : n - 1;       // clamp; duplicates idempotent
      zr[j] = z + (size_t)listRow[q[j]] * DIM;
    }
    float a[RQ];
#pragma unroll
    for (int j = 0; j < RQ; ++j) a[j] = 0.f;
#pragma unroll 2
    for (int d0 = 0; d0 < DIM; d0 += 4) {
      float4 e = *(const float4*)(er + d0);
#pragma unroll
      for (int j = 0; j < RQ; ++j) {
        float4 x = *(const float4*)(zr[j] + d0);
        a[j] = fmaf(x.x, e.x, a[j]);
        a[j] = fmaf(x.y, e.y, a[j]);
        a[j] = fmaf(x.z, e.z, a[j]);
        a[j] = fmaf(x.w, e.w, a[j]);
      }
    }
#pragma unroll
    for (int j = 0; j < RQ; ++j) {
      float t = listS[q[j]] + En;
      float d = t - 2.0f * a[j];
      unsigned long long p =
          ((unsigned long long)__builtin_bit_cast(unsigned int, d) << 32) | (unsigned int)c;
#pragma unroll
      for (int m = 1; m < 64; m <<= 1) {
        unsigned long long o = __shfl_xor(p, m, 64);
        p = o < p ? o : p;
      }
      if ((tid & 63) == 0) sred[tid >> 6][j] = p;
    }
    __syncthreads();
    if (tid < RQ) {
      int j = tid;
      unsigned long long b = sred[0][j];
#pragma unroll
      for (int w2 = 1; w2 < 4; ++w2) b = sred[w2][j] < b ? sred[w2][j] : b;
      atomicMin(&slots[q[j]], b);
    }
    __syncthreads();
  }
}

// ---- epilogue: resolve refined codes, gather e[best], write quantized, loss ----
__global__ __launch_bounds__(256) void vq_epi(const float* __restrict__ z,
                                              const float* __restrict__ emb,
                                              const int* __restrict__ bi,
                                              const int* __restrict__ flagidx,
                                              const unsigned long long* __restrict__ slots,
                                              float* __restrict__ out,
                                              float* __restrict__ outIdx,
                                              float* __restrict__ blockSums) {
  __shared__ float wred[4];
  int tid = threadIdx.x;
  int g = tid >> 4, tl = tid & 15;
  int row = blockIdx.x * 16 + g;
  int fi = flagidx[row];
  int code = bi[row];
  if (fi) {
    code = (int)(unsigned int)slots[fi - 1];
    if (tl == 0) outIdx[row] = (float)code;
  }
  const float* zr = z + (size_t)row * DIM;
  const float* er = emb + (size_t)code * DIM;
  float* oq = out + 1 + (size_t)row * DIM;
  float ls = 0.f;
#pragma unroll
  for (int j = 0; j < 8; ++j) {
    int d0 = (j * 16 + tl) * 4;
    float4 e = *(const float4*)(er + d0);
    float4 zz = *(const float4*)(zr + d0);
    float dx = e.x - zz.x, dy = e.y - zz.y, dz = e.z - zz.z, dw = e.w - zz.w;
    ls = fmaf(dx, dx, ls); ls = fmaf(dy, dy, ls);
    ls = fmaf(dz, dz, ls); ls = fmaf(dw, dw, ls);
    oq[d0 + 0] = e.x; oq[d0 + 1] = e.y; oq[d0 + 2] = e.z; oq[d0 + 3] = e.w;
  }
#pragma unroll
  for (int m = 1; m < 64; m <<= 1) ls += __shfl_xor(ls, m, 64);
  if ((tid & 63) == 0) wred[tid >> 6] = ls;
  __syncthreads();
  if (tid == 0) blockSums[blockIdx.x] = wred[0] + wred[1] + wred[2] + wred[3];
}

// loss = 1.25 * mean((q-z)^2); KL factor 0. 2048 partials.
__global__ __launch_bounds__(256) void vq_final(const float* __restrict__ blockSums,
                                                float* __restrict__ out) {
  __shared__ float red[256];
  int t = threadIdx.x;
  float s = 0.f;
#pragma unroll
  for (int i = 0; i < 8; ++i) s += blockSums[t + i * 256];
  red[t] = s;
  __syncthreads();
  for (int k = 128; k > 0; k >>= 1) {
    if (t < k) red[t] += red[t + k];
    __syncthreads();
  }
  if (t == 0) out[0] = red[0] * (1.25f / 16777216.0f);
}

extern "C" void kernel_launch(void* const* d_in, const int* in_sizes, int n_in,
                              void* d_out, int out_size, void* d_ws, size_t ws_size,
                              hipStream_t stream) {
  const float* z   = (const float*)d_in[0];
  const float* emb = (const float*)d_in[1];
  float* out  = (float*)d_out;
  float* wsf  = (float*)d_ws;
  f16x8* img      = (f16x8*)d_ws;
  float* negHalf  = wsf + OFF_NH;
  float* Enp      = wsf + OFF_EN;
  float* R1s      = wsf + OFF_R1;
  float* R2s      = wsf + OFF_R2;
  int*   I1s      = (int*)(wsf + OFF_I1);
  int*   flagidx  = (int*)(wsf + OFF_FI);
  int*   bi       = (int*)(wsf + OFF_BI);
  float* bsums    = wsf + OFF_BS;
  int*   counter  = (int*)(wsf + OFF_CT);
  int*   listRow  = (int*)(wsf + OFF_LR);
  float* listS    = wsf + OFF_LS;
  unsigned long long* slots = (unsigned long long*)(wsf + OFF_SL);
  float* outIdx   = out + 1 + (size_t)N_ROWS * DIM;
  (void)in_sizes; (void)n_in; (void)out_size; (void)ws_size;

  vq_prep    <<<1024, 256, 0, stream>>>(emb, img, Enp, negHalf, counter);
  vq_main    <<<1024, 256, 0, stream>>>(z, img, negHalf, R1s, R2s, I1s);
  vq_merge   <<<N_ROWS / 256, 256, 0, stream>>>(z, R1s, R2s, I1s, flagidx, bi, outIdx,
                                                counter, listRow, listS, slots);
  vq_rescan  <<<2048, 256, 0, stream>>>(z, emb, Enp, counter, listRow, listS, slots);
  vq_epi     <<<N_ROWS / 16, 256, 0, stream>>>(z, emb, bi, flagidx, slots, out, outIdx, bsums);
  vq_final   <<<1, 256, 0, stream>>>(bsums, out);
}

// Round 18
// 284.633 us; speedup vs baseline: 1.4430x; 1.2437x over previous
//
#include <hip/hip_runtime.h>
#include <cstdint>
#include <cmath>

// Problem: z[32768,512] f32, emb[4096,512] f32
#define N_ROWS 32768
#define DIM    512
#define KCODES 4096
#define SPLITS 4
#define CPS    (KCODES / SPLITS)   // 1024 codes per split
#define KCL    (CPS / 64)          // 16 code-chunks per split
#define BM     128                 // rows per block = 4 waves x 32
#define TAU    2e-3f               // gate threshold on exact noisy scores (proven r5/r8)
#define CAP    1024                // max refined rows (expect ~466; wide headroom)
#define RQ     8                   // rescan rows per thread (ILP + e-reuse)

typedef _Float16 f16x8 __attribute__((ext_vector_type(8)));
typedef float    f32x4 __attribute__((ext_vector_type(4)));

// ---- ws layout (float units) ----
// [0, 1048576): f16 codebook image, 256 tiles x 16KB (4 MB)
#define OFF_NH  1048576                        // negHalf[4096] = -0.5||e||^2
#define OFF_EN  (OFF_NH + KCODES)              // Enp[4096] (np-exact ||e||^2)
#define OFF_R1  (OFF_EN + KCODES)              // R1 [SPLITS][N_ROWS] f32
#define OFF_R2  (OFF_R1 + SPLITS * N_ROWS)     // R2 [SPLITS][N_ROWS] f32
#define OFF_I1  (OFF_R2 + SPLITS * N_ROWS)     // I1 [SPLITS][N_ROWS] i32
#define OFF_FI  (OFF_I1 + SPLITS * N_ROWS)     // flagidx[N_ROWS] i32 (0 or pos+1)
#define OFF_BI  (OFF_FI + N_ROWS)              // best idx[N_ROWS] i32
#define OFF_BS  (OFF_BI + N_ROWS)              // blockSums[2048]
#define OFF_CT  (OFF_BS + 2048)                // counter[4] i32
#define OFF_LR  (OFF_CT + 4)                   // listRow[CAP] i32
#define OFF_LS  (OFF_LR + CAP)                 // listS[CAP] f32
#define OFF_SL  (OFF_LS + CAP)                 // slots[CAP] u64 (even offset -> 8B aligned)

__device__ __forceinline__ bool lexGT(float v1, int i1, float v2, int i2) {
  return (v1 > v2) || (v1 == v2 && i1 < i2);
}

__device__ __forceinline__ void gload16(const void* g, void* l) {
  __builtin_amdgcn_global_load_lds(
      (const __attribute__((address_space(1))) unsigned int*)g,
      (__attribute__((address_space(3))) unsigned int*)l, 16, 0, 0);
}

// ---- numpy fp32 bit-exact helpers (verified rounds 2-5, 8-17) ----
__device__ float np_sumsq_512(const float* __restrict__ a) {
#pragma clang fp contract(off)
  float B[4];
#pragma unroll
  for (int t = 0; t < 4; ++t) {
    const float* p = a + t * 128;
    float r[8];
    {
      float4 x0 = *(const float4*)p;
      float4 x1 = *(const float4*)(p + 4);
      r[0] = x0.x * x0.x; r[1] = x0.y * x0.y; r[2] = x0.z * x0.z; r[3] = x0.w * x0.w;
      r[4] = x1.x * x1.x; r[5] = x1.y * x1.y; r[6] = x1.z * x1.z; r[7] = x1.w * x1.w;
    }
    for (int i = 8; i < 128; i += 8) {
      float4 x0 = *(const float4*)(p + i);
      float4 x1 = *(const float4*)(p + i + 4);
      float f[8] = {x0.x, x0.y, x0.z, x0.w, x1.x, x1.y, x1.z, x1.w};
#pragma unroll
      for (int j = 0; j < 8; ++j) {
        float sq = f[j] * f[j];
        r[j] = r[j] + sq;
      }
    }
    B[t] = ((r[0] + r[1]) + (r[2] + r[3])) + ((r[4] + r[5]) + (r[6] + r[7]));
  }
  return (B[0] + B[1]) + (B[2] + B[3]);
}

// ---- prep (fused): f16 codebook image (inverse mapping -> coalesced img
// writes) + np-exact ||e||^2 + counter zero ----
__global__ __launch_bounds__(256) void vq_prep(const float* __restrict__ emb,
                                               f16x8* __restrict__ img,
                                               float* __restrict__ Enp,
                                               float* __restrict__ negHalf,
                                               int* __restrict__ counter) {
  int gid = blockIdx.x * 256 + threadIdx.x;   // linear img f16x8 slot
  if (gid == 0) counter[0] = 0;
  if (gid < KCODES) {
    float E = np_sumsq_512(emb + (size_t)gid * DIM);
    Enp[gid] = E;
    negHalf[gid] = -0.5f * E;
  }
  // img[gid] <- (code k, d-range) per the fragment-block layout:
  // gid = T*1024 + fb*64 + lane; T=(kcg,dci), fb=(ks,ct), lane=(gh,tl)
  int T = gid >> 10, rem = gid & 1023;
  int fb = rem >> 6, lane = rem & 63;
  int kcg = T >> 2, dci = T & 3;
  int ks = fb >> 2, ct = fb & 3;
  int gh = lane >> 4, tl = lane & 15;
  int k = kcg * 64 + ct * 16 + tl;
  int d = dci * 128 + (ks * 4 + gh) * 8;
  const float* ep = emb + (size_t)k * DIM + d;
  float4 a = *(const float4*)ep;
  float4 b = *(const float4*)(ep + 4);
  float f[8] = {a.x, a.y, a.z, a.w, b.x, b.y, b.z, b.w};
  f16x8 h;
#pragma unroll
  for (int j = 0; j < 8; ++j) h[j] = (_Float16)f[j];
  img[gid] = h;
}

// ---- main: 128 rows x 1024 codes; exact top-1(+index) and top-2(score).
// r18: r15 structure with 2-TILE-WIDE double buffers (2 x 32KB). One
// __syncthreads per 2 tiles instead of per tile: barrier-drain events
// halve (64 -> 32 per block) and each drain is covered by 64 MFMAs
// (~320cyc) instead of 32. Same proven gload16 addressing (wave-uniform
// LDS base), same __syncthreads discipline. Occupancy findings (r16/r17):
// this design needs ~156 total regs -> locked at 2 waves/SIMD; (256,2).
__global__ __launch_bounds__(256, 2) void vq_main(const float* __restrict__ z,
                                                  const f16x8* __restrict__ img,
                                                  const float* __restrict__ negHalf,
                                                  float* __restrict__ R1s,
                                                  float* __restrict__ R2s,
                                                  int* __restrict__ I1s) {
  __shared__ f16x8 EHs[4096];   // 2 x 32KB double buffer (2 tiles each)

  const int tid  = threadIdx.x;
  const int w    = tid >> 6;
  const int lane = tid & 63;
  const int tl   = lane & 15;
  const int gh   = lane >> 4;
  const int bid  = blockIdx.x;
  const int rb   = bid >> 2;       // row-block 0..255
  const int sp   = bid & 3;        // code split 0..3
  const int m0   = rb * BM;

  // resident A: 2 row-tiles x 16 K-chunks of f16x8
  f16x8 zh[2][16];
#pragma unroll
  for (int rt = 0; rt < 2; ++rt) {
    const float* zp = z + (size_t)(m0 + w * 32 + rt * 16 + tl) * DIM + gh * 8;
#pragma unroll
    for (int c = 0; c < 16; ++c) {
      float4 a = *(const float4*)(zp + c * 32);
      float4 b = *(const float4*)(zp + c * 32 + 4);
      float f[8] = {a.x, a.y, a.z, a.w, b.x, b.y, b.z, b.w};
      f16x8 h;
#pragma unroll
      for (int j = 0; j < 8; ++j) h[j] = (_Float16)f[j];
      zh[rt][c] = h;
    }
  }

  // exact running top-1 (score+uniform code base) and top-2 score per row
  float R1[8], R2[8];
  int   I1u[8];
#pragma unroll
  for (int i = 0; i < 8; ++i) { R1[i] = -INFINITY; R2[i] = -INFINITY; I1u[i] = 0x7fffffff; }

  const f16x8* tbase = img + (size_t)sp * 64 * 1024;  // this split's 64 tiles

  // stage tile-PAIR P_ (32KB contiguous) into buffer b_; each wave its 8KB
  // quarter; LDS dest wave-uniform, global per-lane (+lane*16).
#define STAGE_PAIR(P_, b_)                                                         \
  {                                                                                \
    const char* g = (const char*)tbase + (size_t)(P_) * 32768 + w * 8192 + lane * 16; \
    char* l = (char*)EHs + (b_) * 32768 + w * 8192;                                \
    _Pragma("unroll")                                                              \
    for (int i = 0; i < 8; ++i) gload16(g + i * 1024, l + i * 1024);               \
  }

  // prologue: stage pair 0 (tiles 0,1) into buf 0
  STAGE_PAIR(0, 0);
  __syncthreads();

  for (int kcl = 0; kcl < KCL; ++kcl) {
    f32x4 acc[2][4];
#pragma unroll
    for (int ct = 0; ct < 4; ++ct) {
      float nh = negHalf[sp * CPS + kcl * 64 + ct * 16 + tl];
      acc[0][ct] = (f32x4){nh, nh, nh, nh};
      acc[1][ct] = (f32x4){nh, nh, nh, nh};
    }

#pragma unroll
    for (int dcp = 0; dcp < 2; ++dcp) {
      const int t2 = kcl * 2 + dcp;       // pair counter 0..31
      const int cur = t2 & 1;
      if (t2 + 1 < 32) STAGE_PAIR(t2 + 1, cur ^ 1);
      const f16x8* Bp = EHs + cur * 2048;
#pragma unroll
      for (int dcl = 0; dcl < 2; ++dcl) {
        const int dci = dcp * 2 + dcl;
        const f16x8* B = Bp + dcl * 1024;
#pragma unroll
        for (int ks = 0; ks < 4; ++ks) {
          {
            f16x8 bf0 = B[(ks * 4 + 0) * 64 + lane];
            f16x8 bf1 = B[(ks * 4 + 1) * 64 + lane];
            acc[0][0] = __builtin_amdgcn_mfma_f32_16x16x32_f16(zh[0][dci * 4 + ks], bf0, acc[0][0], 0, 0, 0);
            acc[1][0] = __builtin_amdgcn_mfma_f32_16x16x32_f16(zh[1][dci * 4 + ks], bf0, acc[1][0], 0, 0, 0);
            acc[0][1] = __builtin_amdgcn_mfma_f32_16x16x32_f16(zh[0][dci * 4 + ks], bf1, acc[0][1], 0, 0, 0);
            acc[1][1] = __builtin_amdgcn_mfma_f32_16x16x32_f16(zh[1][dci * 4 + ks], bf1, acc[1][1], 0, 0, 0);
          }
          {
            f16x8 bf2 = B[(ks * 4 + 2) * 64 + lane];
            f16x8 bf3 = B[(ks * 4 + 3) * 64 + lane];
            acc[0][2] = __builtin_amdgcn_mfma_f32_16x16x32_f16(zh[0][dci * 4 + ks], bf2, acc[0][2], 0, 0, 0);
            acc[1][2] = __builtin_amdgcn_mfma_f32_16x16x32_f16(zh[1][dci * 4 + ks], bf2, acc[1][2], 0, 0, 0);
            acc[0][3] = __builtin_amdgcn_mfma_f32_16x16x32_f16(zh[0][dci * 4 + ks], bf3, acc[0][3], 0, 0, 0);
            acc[1][3] = __builtin_amdgcn_mfma_f32_16x16x32_f16(zh[1][dci * 4 + ks], bf3, acc[1][3], 0, 0, 0);
          }
        }
      }
      __syncthreads();
    }

    // exact top-1/top-2 insert: 5 VALU per candidate, branchless.
    // Candidates ascend in code order -> strict '>' keeps lowest code on ties.
#pragma unroll
    for (int ct = 0; ct < 4; ++ct) {
      const int cu = sp * CPS + kcl * 64 + ct * 16;   // uniform -> SGPR operand
#pragma unroll
      for (int rt = 0; rt < 2; ++rt)
#pragma unroll
        for (int i = 0; i < 4; ++i) {
          int r8 = rt * 4 + i;
          float v = acc[rt][ct][i];
          float u = fminf(v, R1[r8]);
          R2[r8] = fmaxf(u, R2[r8]);
          bool gt = v > R1[r8];
          R1[r8] = fmaxf(v, R1[r8]);
          I1u[r8] = gt ? cu : I1u[r8];
        }
    }
  }
#undef STAGE_PAIR

  // full per-thread code, then butterfly merge across the 16 tl-lanes
  float R1f[8], R2f[8];
  int   I1f[8];
#pragma unroll
  for (int i = 0; i < 8; ++i) { R1f[i] = R1[i]; R2f[i] = R2[i]; I1f[i] = I1u[i] + tl; }

#pragma unroll
  for (int m = 1; m < 16; m <<= 1) {
#pragma unroll
    for (int i = 0; i < 8; ++i) {
      float o1 = __shfl_xor(R1f[i], m, 16);
      int   p1 = __shfl_xor(I1f[i], m, 16);
      float o2 = __shfl_xor(R2f[i], m, 16);
      R2f[i] = fmaxf(fmaxf(R2f[i], o2), fminf(R1f[i], o1));
      if (lexGT(o1, p1, R1f[i], I1f[i])) { R1f[i] = o1; I1f[i] = p1; }
    }
  }

  if (tl == 0) {
#pragma unroll
    for (int i = 0; i < 8; ++i) {
      int row = m0 + w * 32 + (i >> 2) * 16 + gh * 4 + (i & 3);
      R1s[(size_t)sp * N_ROWS + row] = R1f[i];
      R2s[(size_t)sp * N_ROWS + row] = R2f[i];
      I1s[(size_t)sp * N_ROWS + row] = I1f[i];
    }
  }
}

// ---- merge 4 splits per row; compact near-tie rows into a work list ----
__global__ __launch_bounds__(256) void vq_merge(const float* __restrict__ z,
                                                const float* __restrict__ R1s,
                                                const float* __restrict__ R2s,
                                                const int* __restrict__ I1s,
                                                int* __restrict__ flagidx,
                                                int* __restrict__ bi,
                                                float* __restrict__ outIdx,
                                                int* __restrict__ counter,
                                                int* __restrict__ listRow,
                                                float* __restrict__ listS,
                                                unsigned long long* __restrict__ slots) {
  int row = blockIdx.x * 256 + threadIdx.x;
  float bR = -INFINITY, sec = -INFINITY;
  int bI = 0x7fffffff;
#pragma unroll
  for (int s = 0; s < 4; ++s) {
    float r1 = R1s[(size_t)s * N_ROWS + row];
    float r2 = R2s[(size_t)s * N_ROWS + row];
    int   i1 = I1s[(size_t)s * N_ROWS + row];
    sec = fmaxf(fmaxf(sec, r2), fminf(bR, r1));
    if (lexGT(r1, i1, bR, bI)) { bR = r1; bI = i1; }
  }
  bi[row] = bI;
  outIdx[row] = (float)bI;
  int fi = 0;
  if (bR - sec < TAU) {
#pragma clang fp contract(off)
    int pos = atomicAdd(counter, 1);
    if (pos < CAP) {
      listRow[pos] = row;
      listS[pos]   = np_sumsq_512(z + (size_t)row * DIM);
      slots[pos]   = ~0ull;
      fi = pos + 1;
    }
  }
  flagidx[row] = fi;
}

// ---- rescan: full np-exact argmin over all 4096 codes for listed rows.
// Grid = 16 code-chunks x 128 row-groups (2048 blocks); RQ=8 rows/thread,
// single pass for n <= 1024. 8 independent fma chains hide load latency.
__global__ __launch_bounds__(256) void vq_rescan(const float* __restrict__ z,
                                                 const float* __restrict__ emb,
                                                 const float* __restrict__ Enp,
                                                 const int* __restrict__ counter,
                                                 const int* __restrict__ listRow,
                                                 const float* __restrict__ listS,
                                                 unsigned long long* __restrict__ slots) {
  __shared__ unsigned long long sred[4][RQ];
  const int tid = threadIdx.x;
  const int ci  = blockIdx.x & 15;     // code chunk (e-rows fixed per thread)
  const int gi  = blockIdx.x >> 4;     // row group 0..127
  const int c   = ci * 256 + tid;
  const float* er = emb + (size_t)c * DIM;
  const float En = Enp[c];
  int n = counter[0];
  if (n > CAP) n = CAP;
  for (int qt = gi * RQ; qt < n; qt += 128 * RQ) {
#pragma clang fp contract(off)
    int q[RQ];
    const float* zr[RQ];
#pragma unroll
    for (int j = 0; j < RQ; ++j) {
      int qq = qt + j;
      q[j] = qq < n ? qq : n - 1;       // clamp; duplicates idempotent
      zr[j] = z + (size_t)listRow[q[j]] * DIM;
    }
    float a[RQ];
#pragma unroll
    for (int j = 0; j < RQ; ++j) a[j] = 0.f;
#pragma unroll 2
    for (int d0 = 0; d0 < DIM; d0 += 4) {
      float4 e = *(const float4*)(er + d0);
#pragma unroll
      for (int j = 0; j < RQ; ++j) {
        float4 x = *(const float4*)(zr[j] + d0);
        a[j] = fmaf(x.x, e.x, a[j]);
        a[j] = fmaf(x.y, e.y, a[j]);
        a[j] = fmaf(x.z, e.z, a[j]);
        a[j] = fmaf(x.w, e.w, a[j]);
      }
    }
#pragma unroll
    for (int j = 0; j < RQ; ++j) {
      float t = listS[q[j]] + En;
      float d = t - 2.0f * a[j];
      unsigned long long p =
          ((unsigned long long)__builtin_bit_cast(unsigned int, d) << 32) | (unsigned int)c;
#pragma unroll
      for (int m = 1; m < 64; m <<= 1) {
        unsigned long long o = __shfl_xor(p, m, 64);
        p = o < p ? o : p;
      }
      if ((tid & 63) == 0) sred[tid >> 6][j] = p;
    }
    __syncthreads();
    if (tid < RQ) {
      int j = tid;
      unsigned long long b = sred[0][j];
#pragma unroll
      for (int w2 = 1; w2 < 4; ++w2) b = sred[w2][j] < b ? sred[w2][j] : b;
      atomicMin(&slots[q[j]], b);
    }
    __syncthreads();
  }
}

// ---- epilogue: resolve refined codes, gather e[best], write quantized, loss ----
__global__ __launch_bounds__(256) void vq_epi(const float* __restrict__ z,
                                              const float* __restrict__ emb,
                                              const int* __restrict__ bi,
                                              const int* __restrict__ flagidx,
                                              const unsigned long long* __restrict__ slots,
                                              float* __restrict__ out,
                                              float* __restrict__ outIdx,
                                              float* __restrict__ blockSums) {
  __shared__ float wred[4];
  int tid = threadIdx.x;
  int g = tid >> 4, tl = tid & 15;
  int row = blockIdx.x * 16 + g;
  int fi = flagidx[row];
  int code = bi[row];
  if (fi) {
    code = (int)(unsigned int)slots[fi - 1];
    if (tl == 0) outIdx[row] = (float)code;
  }
  const float* zr = z + (size_t)row * DIM;
  const float* er = emb + (size_t)code * DIM;
  float* oq = out + 1 + (size_t)row * DIM;
  float ls = 0.f;
#pragma unroll
  for (int j = 0; j < 8; ++j) {
    int d0 = (j * 16 + tl) * 4;
    float4 e = *(const float4*)(er + d0);
    float4 zz = *(const float4*)(zr + d0);
    float dx = e.x - zz.x, dy = e.y - zz.y, dz = e.z - zz.z, dw = e.w - zz.w;
    ls = fmaf(dx, dx, ls); ls = fmaf(dy, dy, ls);
    ls = fmaf(dz, dz, ls); ls = fmaf(dw, dw, ls);
    oq[d0 + 0] = e.x; oq[d0 + 1] = e.y; oq[d0 + 2] = e.z; oq[d0 + 3] = e.w;
  }
#pragma unroll
  for (int m = 1; m < 64; m <<= 1) ls += __shfl_xor(ls, m, 64);
  if ((tid & 63) == 0) wred[tid >> 6] = ls;
  __syncthreads();
  if (tid == 0) blockSums[blockIdx.x] = wred[0] + wred[1] + wred[2] + wred[3];
}

// loss = 1.25 * mean((q-z)^2); KL factor 0. 2048 partials.
__global__ __launch_bounds__(256) void vq_final(const float* __restrict__ blockSums,
                                                float* __restrict__ out) {
  __shared__ float red[256];
  int t = threadIdx.x;
  float s = 0.f;
#pragma unroll
  for (int i = 0; i < 8; ++i) s += blockSums[t + i * 256];
  red[t] = s;
  __syncthreads();
  for (int k = 128; k > 0; k >>= 1) {
    if (t < k) red[t] += red[t + k];
    __syncthreads();
  }
  if (t == 0) out[0] = red[0] * (1.25f / 16777216.0f);
}

extern "C" void kernel_launch(void* const* d_in, const int* in_sizes, int n_in,
                              void* d_out, int out_size, void* d_ws, size_t ws_size,
                              hipStream_t stream) {
  const float* z   = (const float*)d_in[0];
  const float* emb = (const float*)d_in[1];
  float* out  = (float*)d_out;
  float* wsf  = (float*)d_ws;
  f16x8* img      = (f16x8*)d_ws;
  float* negHalf  = wsf + OFF_NH;
  float* Enp      = wsf + OFF_EN;
  float* R1s      = wsf + OFF_R1;
  float* R2s      = wsf + OFF_R2;
  int*   I1s      = (int*)(wsf + OFF_I1);
  int*   flagidx  = (int*)(wsf + OFF_FI);
  int*   bi       = (int*)(wsf + OFF_BI);
  float* bsums    = wsf + OFF_BS;
  int*   counter  = (int*)(wsf + OFF_CT);
  int*   listRow  = (int*)(wsf + OFF_LR);
  float* listS    = wsf + OFF_LS;
  unsigned long long* slots = (unsigned long long*)(wsf + OFF_SL);
  float* outIdx   = out + 1 + (size_t)N_ROWS * DIM;
  (void)in_sizes; (void)n_in; (void)out_size; (void)ws_size;

  vq_prep    <<<1024, 256, 0, stream>>>(emb, img, Enp, negHalf, counter);
  vq_main    <<<1024, 256, 0, stream>>>(z, img, negHalf, R1s, R2s, I1s);
  vq_merge   <<<N_ROWS / 256, 256, 0, stream>>>(z, R1s, R2s, I1s, flagidx, bi, outIdx,
                                                counter, listRow, listS, slots);
  vq_rescan  <<<2048, 256, 0, stream>>>(z, emb, Enp, counter, listRow, listS, slots);
  vq_epi     <<<N_ROWS / 16, 256, 0, stream>>>(z, emb, bi, flagidx, slots, out, outIdx, bsums);
  vq_final   <<<1, 256, 0, stream>>>(bsums, out);
}

// Round 19
// 275.514 us; speedup vs baseline: 1.4907x; 1.0331x over previous
//
#include <hip/hip_runtime.h>
#include <cstdint>
#include <cmath>

// Problem: z[32768,512] f32, emb[4096,512] f32
#define N_ROWS 32768
#define DIM    512
#define KCODES 4096
#define SPLITS 2
#define CPS    (KCODES / SPLITS)   // 2048 codes per split
#define KCL    (CPS / 64)          // 32 code-chunks per split
#define TPS    (KCL * 4)           // 128 tiles per split
#define BM     128                 // rows per block = 4 waves x 32
#define TAU    2e-3f               // gate threshold on exact noisy scores (proven r5/r8)
#define CAP    1024                // max refined rows (expect ~466; wide headroom)
#define RQ     8                   // rescan rows per thread (ILP + e-reuse)

typedef _Float16 f16x8 __attribute__((ext_vector_type(8)));
typedef float    f32x4 __attribute__((ext_vector_type(4)));

// ---- ws layout (float units) ----
// [0, 1048576): f16 codebook image, 256 tiles x 16KB (4 MB)
#define OFF_NH  1048576                        // negHalf[4096] = -0.5||e||^2
#define OFF_EN  (OFF_NH + KCODES)              // Enp[4096] (np-exact ||e||^2)
#define OFF_R1  (OFF_EN + KCODES)              // R1 [SPLITS][N_ROWS] f32
#define OFF_R2  (OFF_R1 + SPLITS * N_ROWS)     // R2 [SPLITS][N_ROWS] f32
#define OFF_I1  (OFF_R2 + SPLITS * N_ROWS)     // I1 [SPLITS][N_ROWS] i32
#define OFF_FI  (OFF_I1 + SPLITS * N_ROWS)     // flagidx[N_ROWS] i32 (0 or pos+1)
#define OFF_BI  (OFF_FI + N_ROWS)              // best idx[N_ROWS] i32
#define OFF_BS  (OFF_BI + N_ROWS)              // blockSums[2048]
#define OFF_CT  (OFF_BS + 2048)                // counter[4] i32
#define OFF_LR  (OFF_CT + 4)                   // listRow[CAP] i32
#define OFF_LS  (OFF_LR + CAP)                 // listS[CAP] f32
#define OFF_SL  (OFF_LS + CAP)                 // slots[CAP] u64 (even offset -> 8B aligned)

__device__ __forceinline__ bool lexGT(float v1, int i1, float v2, int i2) {
  return (v1 > v2) || (v1 == v2 && i1 < i2);
}

__device__ __forceinline__ void gload16(const void* g, void* l) {
  __builtin_amdgcn_global_load_lds(
      (const __attribute__((address_space(1))) unsigned int*)g,
      (__attribute__((address_space(3))) unsigned int*)l, 16, 0, 0);
}

// ---- numpy fp32 bit-exact helpers (verified rounds 2-5, 8-18) ----
__device__ float np_sumsq_512(const float* __restrict__ a) {
#pragma clang fp contract(off)
  float B[4];
#pragma unroll
  for (int t = 0; t < 4; ++t) {
    const float* p = a + t * 128;
    float r[8];
    {
      float4 x0 = *(const float4*)p;
      float4 x1 = *(const float4*)(p + 4);
      r[0] = x0.x * x0.x; r[1] = x0.y * x0.y; r[2] = x0.z * x0.z; r[3] = x0.w * x0.w;
      r[4] = x1.x * x1.x; r[5] = x1.y * x1.y; r[6] = x1.z * x1.z; r[7] = x1.w * x1.w;
    }
    for (int i = 8; i < 128; i += 8) {
      float4 x0 = *(const float4*)(p + i);
      float4 x1 = *(const float4*)(p + i + 4);
      float f[8] = {x0.x, x0.y, x0.z, x0.w, x1.x, x1.y, x1.z, x1.w};
#pragma unroll
      for (int j = 0; j < 8; ++j) {
        float sq = f[j] * f[j];
        r[j] = r[j] + sq;
      }
    }
    B[t] = ((r[0] + r[1]) + (r[2] + r[3])) + ((r[4] + r[5]) + (r[6] + r[7]));
  }
  return (B[0] + B[1]) + (B[2] + B[3]);
}

// ---- prep (fused): f16 codebook image (inverse mapping -> coalesced img
// writes) + np-exact ||e||^2 + counter zero ----
__global__ __launch_bounds__(256) void vq_prep(const float* __restrict__ emb,
                                               f16x8* __restrict__ img,
                                               float* __restrict__ Enp,
                                               float* __restrict__ negHalf,
                                               int* __restrict__ counter) {
  int gid = blockIdx.x * 256 + threadIdx.x;   // linear img f16x8 slot
  if (gid == 0) counter[0] = 0;
  if (gid < KCODES) {
    float E = np_sumsq_512(emb + (size_t)gid * DIM);
    Enp[gid] = E;
    negHalf[gid] = -0.5f * E;
  }
  // img[gid] <- (code k, d-range) per the fragment-block layout:
  // gid = T*1024 + fb*64 + lane; T=(kcg,dci), fb=(ks,ct), lane=(gh,tl)
  int T = gid >> 10, rem = gid & 1023;
  int fb = rem >> 6, lane = rem & 63;
  int kcg = T >> 2, dci = T & 3;
  int ks = fb >> 2, ct = fb & 3;
  int gh = lane >> 4, tl = lane & 15;
  int k = kcg * 64 + ct * 16 + tl;
  int d = dci * 128 + (ks * 4 + gh) * 8;
  const float* ep = emb + (size_t)k * DIM + d;
  float4 a = *(const float4*)ep;
  float4 b = *(const float4*)(ep + 4);
  float f[8] = {a.x, a.y, a.z, a.w, b.x, b.y, b.z, b.w};
  f16x8 h;
#pragma unroll
  for (int j = 0; j < 8; ++j) h[j] = (_Float16)f[j];
  img[gid] = h;
}

// ---- main: 128 rows x 2048 codes; exact top-1(+index) and top-2(score).
// r19: SPLITS=2 (grid 512 = exactly 2 blocks/CU; co-resident blocks share
// the same z rows -> z read traffic and prologue conversion HALVE vs
// SPLITS=4) + top-2 insert hoisted BEFORE the kcl-boundary barrier (the
// 160-VALU insert now covers the staging drain instead of waiting on it).
// Core loop structure = proven r15 (164us): 2x16KB dbuf, gload16 staging
// (wave-uniform LDS base), 1 barrier/tile otherwise. Register findings
// (r16/r17): ~156 total regs -> locked at 2 waves/SIMD; (256,2) is final.
__global__ __launch_bounds__(256, 2) void vq_main(const float* __restrict__ z,
                                                  const f16x8* __restrict__ img,
                                                  const float* __restrict__ negHalf,
                                                  float* __restrict__ R1s,
                                                  float* __restrict__ R2s,
                                                  int* __restrict__ I1s) {
  __shared__ f16x8 EHs[2048];   // 2 x 16KB double buffer

  const int tid  = threadIdx.x;
  const int w    = tid >> 6;
  const int lane = tid & 63;
  const int tl   = lane & 15;
  const int gh   = lane >> 4;
  const int bid  = blockIdx.x;
  const int rb   = bid >> 1;       // row-block 0..255
  const int sp   = bid & 1;        // code split 0..1
  const int m0   = rb * BM;

  // resident A: 2 row-tiles x 16 K-chunks of f16x8
  f16x8 zh[2][16];
#pragma unroll
  for (int rt = 0; rt < 2; ++rt) {
    const float* zp = z + (size_t)(m0 + w * 32 + rt * 16 + tl) * DIM + gh * 8;
#pragma unroll
    for (int c = 0; c < 16; ++c) {
      float4 a = *(const float4*)(zp + c * 32);
      float4 b = *(const float4*)(zp + c * 32 + 4);
      float f[8] = {a.x, a.y, a.z, a.w, b.x, b.y, b.z, b.w};
      f16x8 h;
#pragma unroll
      for (int j = 0; j < 8; ++j) h[j] = (_Float16)f[j];
      zh[rt][c] = h;
    }
  }

  // exact running top-1 (score+uniform code base) and top-2 score per row
  float R1[8], R2[8];
  int   I1u[8];
#pragma unroll
  for (int i = 0; i < 8; ++i) { R1[i] = -INFINITY; R2[i] = -INFINITY; I1u[i] = 0x7fffffff; }

  const f16x8* tbase = img + (size_t)sp * TPS * 1024;  // this split's 128 tiles

  // prologue: stage tile 0 into buf 0 (each wave its 4KB quarter)
  {
    const char* g = (const char*)tbase + w * 4096 + lane * 16;
    char* l = (char*)EHs + w * 4096;
#pragma unroll
    for (int i = 0; i < 4; ++i) gload16(g + i * 1024, l + i * 1024);
  }
  __syncthreads();

  for (int kcl = 0; kcl < KCL; ++kcl) {
    f32x4 acc[2][4];
#pragma unroll
    for (int ct = 0; ct < 4; ++ct) {
      float nh = negHalf[sp * CPS + kcl * 64 + ct * 16 + tl];
      acc[0][ct] = (f32x4){nh, nh, nh, nh};
      acc[1][ct] = (f32x4){nh, nh, nh, nh};
    }

#pragma unroll
    for (int dci = 0; dci < 4; ++dci) {
      const int t = kcl * 4 + dci;
      const int cur = t & 1;
      if (t + 1 < TPS) {  // stage next tile into the other buffer
        const char* g = (const char*)(tbase + (size_t)(t + 1) * 1024) + w * 4096 + lane * 16;
        char* l = (char*)EHs + (cur ^ 1) * 16384 + w * 4096;
#pragma unroll
        for (int i = 0; i < 4; ++i) gload16(g + i * 1024, l + i * 1024);
      }
      const f16x8* B = EHs + cur * 1024;
#pragma unroll
      for (int ks = 0; ks < 4; ++ks) {
        {
          f16x8 bf0 = B[(ks * 4 + 0) * 64 + lane];
          f16x8 bf1 = B[(ks * 4 + 1) * 64 + lane];
          acc[0][0] = __builtin_amdgcn_mfma_f32_16x16x32_f16(zh[0][dci * 4 + ks], bf0, acc[0][0], 0, 0, 0);
          acc[1][0] = __builtin_amdgcn_mfma_f32_16x16x32_f16(zh[1][dci * 4 + ks], bf0, acc[1][0], 0, 0, 0);
          acc[0][1] = __builtin_amdgcn_mfma_f32_16x16x32_f16(zh[0][dci * 4 + ks], bf1, acc[0][1], 0, 0, 0);
          acc[1][1] = __builtin_amdgcn_mfma_f32_16x16x32_f16(zh[1][dci * 4 + ks], bf1, acc[1][1], 0, 0, 0);
        }
        {
          f16x8 bf2 = B[(ks * 4 + 2) * 64 + lane];
          f16x8 bf3 = B[(ks * 4 + 3) * 64 + lane];
          acc[0][2] = __builtin_amdgcn_mfma_f32_16x16x32_f16(zh[0][dci * 4 + ks], bf2, acc[0][2], 0, 0, 0);
          acc[1][2] = __builtin_amdgcn_mfma_f32_16x16x32_f16(zh[1][dci * 4 + ks], bf2, acc[1][2], 0, 0, 0);
          acc[0][3] = __builtin_amdgcn_mfma_f32_16x16x32_f16(zh[0][dci * 4 + ks], bf3, acc[0][3], 0, 0, 0);
          acc[1][3] = __builtin_amdgcn_mfma_f32_16x16x32_f16(zh[1][dci * 4 + ks], bf3, acc[1][3], 0, 0, 0);
        }
      }
      if (dci < 3) __syncthreads();
      // dci==3: barrier deferred until after the insert below (insert is
      // pure VALU/register work -> it overlaps the staging drain; buffer
      // invariant unchanged since the barrier still precedes the next
      // overwrite of buf(cur)).
    }

    // exact top-1/top-2 insert: 5 VALU per candidate, branchless.
    // Candidates ascend in code order -> strict '>' keeps lowest code on ties.
#pragma unroll
    for (int ct = 0; ct < 4; ++ct) {
      const int cu = sp * CPS + kcl * 64 + ct * 16;   // uniform -> SGPR operand
#pragma unroll
      for (int rt = 0; rt < 2; ++rt)
#pragma unroll
        for (int i = 0; i < 4; ++i) {
          int r8 = rt * 4 + i;
          float v = acc[rt][ct][i];
          float u = fminf(v, R1[r8]);
          R2[r8] = fmaxf(u, R2[r8]);
          bool gt = v > R1[r8];
          R1[r8] = fmaxf(v, R1[r8]);
          I1u[r8] = gt ? cu : I1u[r8];
        }
    }
    __syncthreads();   // deferred kcl-boundary barrier
  }

  // full per-thread code, then butterfly merge across the 16 tl-lanes
  float R1f[8], R2f[8];
  int   I1f[8];
#pragma unroll
  for (int i = 0; i < 8; ++i) { R1f[i] = R1[i]; R2f[i] = R2[i]; I1f[i] = I1u[i] + tl; }

#pragma unroll
  for (int m = 1; m < 16; m <<= 1) {
#pragma unroll
    for (int i = 0; i < 8; ++i) {
      float o1 = __shfl_xor(R1f[i], m, 16);
      int   p1 = __shfl_xor(I1f[i], m, 16);
      float o2 = __shfl_xor(R2f[i], m, 16);
      R2f[i] = fmaxf(fmaxf(R2f[i], o2), fminf(R1f[i], o1));
      if (lexGT(o1, p1, R1f[i], I1f[i])) { R1f[i] = o1; I1f[i] = p1; }
    }
  }

  if (tl == 0) {
#pragma unroll
    for (int i = 0; i < 8; ++i) {
      int row = m0 + w * 32 + (i >> 2) * 16 + gh * 4 + (i & 3);
      R1s[(size_t)sp * N_ROWS + row] = R1f[i];
      R2s[(size_t)sp * N_ROWS + row] = R2f[i];
      I1s[(size_t)sp * N_ROWS + row] = I1f[i];
    }
  }
}

// ---- merge 2 splits per row; compact near-tie rows into a work list ----
__global__ __launch_bounds__(256) void vq_merge(const float* __restrict__ z,
                                                const float* __restrict__ R1s,
                                                const float* __restrict__ R2s,
                                                const int* __restrict__ I1s,
                                                int* __restrict__ flagidx,
                                                int* __restrict__ bi,
                                                float* __restrict__ outIdx,
                                                int* __restrict__ counter,
                                                int* __restrict__ listRow,
                                                float* __restrict__ listS,
                                                unsigned long long* __restrict__ slots) {
  int row = blockIdx.x * 256 + threadIdx.x;
  float bR = -INFINITY, sec = -INFINITY;
  int bI = 0x7fffffff;
#pragma unroll
  for (int s = 0; s < SPLITS; ++s) {
    float r1 = R1s[(size_t)s * N_ROWS + row];
    float r2 = R2s[(size_t)s * N_ROWS + row];
    int   i1 = I1s[(size_t)s * N_ROWS + row];
    sec = fmaxf(fmaxf(sec, r2), fminf(bR, r1));
    if (lexGT(r1, i1, bR, bI)) { bR = r1; bI = i1; }
  }
  bi[row] = bI;
  outIdx[row] = (float)bI;
  int fi = 0;
  if (bR - sec < TAU) {
#pragma clang fp contract(off)
    int pos = atomicAdd(counter, 1);
    if (pos < CAP) {
      listRow[pos] = row;
      listS[pos]   = np_sumsq_512(z + (size_t)row * DIM);
      slots[pos]   = ~0ull;
      fi = pos + 1;
    }
  }
  flagidx[row] = fi;
}

// ---- rescan: full np-exact argmin over all 4096 codes for listed rows.
// Grid = 16 code-chunks x 128 row-groups (2048 blocks); RQ=8 rows/thread,
// single pass for n <= 1024. 8 independent fma chains hide load latency.
__global__ __launch_bounds__(256) void vq_rescan(const float* __restrict__ z,
                                                 const float* __restrict__ emb,
                                                 const float* __restrict__ Enp,
                                                 const int* __restrict__ counter,
                                                 const int* __restrict__ listRow,
                                                 const float* __restrict__ listS,
                                                 unsigned long long* __restrict__ slots) {
  __shared__ unsigned long long sred[4][RQ];
  const int tid = threadIdx.x;
  const int ci  = blockIdx.x & 15;     // code chunk (e-rows fixed per thread)
  const int gi  = blockIdx.x >> 4;     // row group 0..127
  const int c   = ci * 256 + tid;
  const float* er = emb + (size_t)c * DIM;
  const float En = Enp[c];
  int n = counter[0];
  if (n > CAP) n = CAP;
  for (int qt = gi * RQ; qt < n; qt += 128 * RQ) {
#pragma clang fp contract(off)
    int q[RQ];
    const float* zr[RQ];
#pragma unroll
    for (int j = 0; j < RQ; ++j) {
      int qq = qt + j;
      q[j] = qq < n ? qq : n - 1;       // clamp; duplicates idempotent
      zr[j] = z + (size_t)listRow[q[j]] * DIM;
    }
    float a[RQ];
#pragma unroll
    for (int j = 0; j < RQ; ++j) a[j] = 0.f;
#pragma unroll 2
    for (int d0 = 0; d0 < DIM; d0 += 4) {
      float4 e = *(const float4*)(er + d0);
#pragma unroll
      for (int j = 0; j < RQ; ++j) {
        float4 x = *(const float4*)(zr[j] + d0);
        a[j] = fmaf(x.x, e.x, a[j]);
        a[j] = fmaf(x.y, e.y, a[j]);
        a[j] = fmaf(x.z, e.z, a[j]);
        a[j] = fmaf(x.w, e.w, a[j]);
      }
    }
#pragma unroll
    for (int j = 0; j < RQ; ++j) {
      float t = listS[q[j]] + En;
      float d = t - 2.0f * a[j];
      unsigned long long p =
          ((unsigned long long)__builtin_bit_cast(unsigned int, d) << 32) | (unsigned int)c;
#pragma unroll
      for (int m = 1; m < 64; m <<= 1) {
        unsigned long long o = __shfl_xor(p, m, 64);
        p = o < p ? o : p;
      }
      if ((tid & 63) == 0) sred[tid >> 6][j] = p;
    }
    __syncthreads();
    if (tid < RQ) {
      int j = tid;
      unsigned long long b = sred[0][j];
#pragma unroll
      for (int w2 = 1; w2 < 4; ++w2) b = sred[w2][j] < b ? sred[w2][j] : b;
      atomicMin(&slots[q[j]], b);
    }
    __syncthreads();
  }
}

// ---- epilogue: resolve refined codes, gather e[best], write quantized, loss ----
__global__ __launch_bounds__(256) void vq_epi(const float* __restrict__ z,
                                              const float* __restrict__ emb,
                                              const int* __restrict__ bi,
                                              const int* __restrict__ flagidx,
                                              const unsigned long long* __restrict__ slots,
                                              float* __restrict__ out,
                                              float* __restrict__ outIdx,
                                              float* __restrict__ blockSums) {
  __shared__ float wred[4];
  int tid = threadIdx.x;
  int g = tid >> 4, tl = tid & 15;
  int row = blockIdx.x * 16 + g;
  int fi = flagidx[row];
  int code = bi[row];
  if (fi) {
    code = (int)(unsigned int)slots[fi - 1];
    if (tl == 0) outIdx[row] = (float)code;
  }
  const float* zr = z + (size_t)row * DIM;
  const float* er = emb + (size_t)code * DIM;
  float* oq = out + 1 + (size_t)row * DIM;
  float ls = 0.f;
#pragma unroll
  for (int j = 0; j < 8; ++j) {
    int d0 = (j * 16 + tl) * 4;
    float4 e = *(const float4*)(er + d0);
    float4 zz = *(const float4*)(zr + d0);
    float dx = e.x - zz.x, dy = e.y - zz.y, dz = e.z - zz.z, dw = e.w - zz.w;
    ls = fmaf(dx, dx, ls); ls = fmaf(dy, dy, ls);
    ls = fmaf(dz, dz, ls); ls = fmaf(dw, dw, ls);
    oq[d0 + 0] = e.x; oq[d0 + 1] = e.y; oq[d0 + 2] = e.z; oq[d0 + 3] = e.w;
  }
#pragma unroll
  for (int m = 1; m < 64; m <<= 1) ls += __shfl_xor(ls, m, 64);
  if ((tid & 63) == 0) wred[tid >> 6] = ls;
  __syncthreads();
  if (tid == 0) blockSums[blockIdx.x] = wred[0] + wred[1] + wred[2] + wred[3];
}

// loss = 1.25 * mean((q-z)^2); KL factor 0. 2048 partials.
__global__ __launch_bounds__(256) void vq_final(const float* __restrict__ blockSums,
                                                float* __restrict__ out) {
  __shared__ float red[256];
  int t = threadIdx.x;
  float s = 0.f;
#pragma unroll
  for (int i = 0; i < 8; ++i) s += blockSums[t + i * 256];
  red[t] = s;
  __syncthreads();
  for (int k = 128; k > 0; k >>= 1) {
    if (t < k) red[t] += red[t + k];
    __syncthreads();
  }
  if (t == 0) out[0] = red[0] * (1.25f / 16777216.0f);
}

extern "C" void kernel_launch(void* const* d_in, const int* in_sizes, int n_in,
                              void* d_out, int out_size, void* d_ws, size_t ws_size,
                              hipStream_t stream) {
  const float* z   = (const float*)d_in[0];
  const float* emb = (const float*)d_in[1];
  float* out  = (float*)d_out;
  float* wsf  = (float*)d_ws;
  f16x8* img      = (f16x8*)d_ws;
  float* negHalf  = wsf + OFF_NH;
  float* Enp      = wsf + OFF_EN;
  float* R1s      = wsf + OFF_R1;
  float* R2s      = wsf + OFF_R2;
  int*   I1s      = (int*)(wsf + OFF_I1);
  int*   flagidx  = (int*)(wsf + OFF_FI);
  int*   bi       = (int*)(wsf + OFF_BI);
  float* bsums    = wsf + OFF_BS;
  int*   counter  = (int*)(wsf + OFF_CT);
  int*   listRow  = (int*)(wsf + OFF_LR);
  float* listS    = wsf + OFF_LS;
  unsigned long long* slots = (unsigned long long*)(wsf + OFF_SL);
  float* outIdx   = out + 1 + (size_t)N_ROWS * DIM;
  (void)in_sizes; (void)n_in; (void)out_size; (void)ws_size;

  vq_prep    <<<1024, 256, 0, stream>>>(emb, img, Enp, negHalf, counter);
  vq_main    <<<N_ROWS / BM * SPLITS, 256, 0, stream>>>(z, img, negHalf, R1s, R2s, I1s);
  vq_merge   <<<N_ROWS / 256, 256, 0, stream>>>(z, R1s, R2s, I1s, flagidx, bi, outIdx,
                                                counter, listRow, listS, slots);
  vq_rescan  <<<2048, 256, 0, stream>>>(z, emb, Enp, counter, listRow, listS, slots);
  vq_epi     <<<N_ROWS / 16, 256, 0, stream>>>(z, emb, bi, flagidx, slots, out, outIdx, bsums);
  vq_final   <<<1, 256, 0, stream>>>(bsums, out);
}